// Round 1
// baseline (553.723 us; speedup 1.0000x reference)
//
#include <hip/hip_runtime.h>
#include <cstdint>
#include <cstddef>

#define NPTS 8192
#define DF   512
#define NCLS 128
#define MAXM 192

typedef __attribute__((ext_vector_type(8))) short   short8;
typedef __attribute__((ext_vector_type(8))) __bf16  bf16x8;
typedef __attribute__((ext_vector_type(4))) float   f32x4;
typedef __attribute__((ext_vector_type(4))) float   f4;

// ---------------- prep: fp32 -> bf16 copy + row squared norms ----------------
__global__ void prep_kernel(const float* __restrict__ E,
                            unsigned short* __restrict__ Ebf,
                            float* __restrict__ sq) {
  const int row  = blockIdx.x * 4 + (threadIdx.x >> 6);
  const int lane = threadIdx.x & 63;
  const float* rp = E + (size_t)row * DF + lane * 8;
  f4 x0 = *reinterpret_cast<const f4*>(rp);
  f4 x1 = *reinterpret_cast<const f4*>(rp + 4);
  float x[8] = {x0.x, x0.y, x0.z, x0.w, x1.x, x1.y, x1.z, x1.w};
  float s = 0.f;
  short8 o;
#pragma unroll
  for (int j = 0; j < 8; ++j) {
    s += x[j] * x[j];
    uint32_t u = __float_as_uint(x[j]);
    u += 0x7FFFu + ((u >> 16) & 1u);   // round-to-nearest-even bf16
    o[j] = (short)(u >> 16);
  }
  *reinterpret_cast<short8*>(Ebf + (size_t)row * DF + lane * 8) = o;
#pragma unroll
  for (int d = 1; d < 64; d <<= 1) s += __shfl_xor(s, d);
  if (lane == 0) sq[row] = s;
}

// ---------------- deterministic class member lists (wave ballot scan) --------
__global__ void build_lists_kernel(const long long* __restrict__ labels,
                                   int* __restrict__ cnt,
                                   int* __restrict__ members) {
  const int c    = blockIdx.x;     // one wave per class
  const int lane = threadIdx.x;    // blockDim = 64
  int base = 0;
  for (int chunk = 0; chunk < NPTS / 64; ++chunk) {
    const int idx = chunk * 64 + lane;
    const int lab = (int)labels[idx];
    const unsigned long long mask = __ballot(lab == c);
    if (lab == c) {
      const int prefix = __popcll(mask & ((1ull << lane) - 1ull));
      if (base + prefix < MAXM) members[c * MAXM + base + prefix] = idx;
    }
    base += __popcll(mask);
  }
  if (lane == 0) cnt[c] = (base < MAXM) ? base : MAXM;
}

// ---------------- main: bf16 MFMA Gram + fused masked partial LSE ------------
__global__ __launch_bounds__(256, 2)
void gram_lse_kernel(const unsigned short* __restrict__ Ebf,
                     const float* __restrict__ sq,
                     const long long* __restrict__ labels,
                     float* __restrict__ Pm, float* __restrict__ Ps) {
  __shared__ unsigned short As[128 * 64];   // 16 KiB, XOR-swizzled 16B chunks
  __shared__ unsigned short Bs[128 * 64];   // 16 KiB

  const int tid  = threadIdx.x;
  const int lane = tid & 63;
  const int wv   = tid >> 6;
  const int wr   = wv >> 1, wc = wv & 1;
  const int brow = blockIdx.y * 128;
  const int bcol = blockIdx.x * 128;

  const int srow   = lane >> 3;            // staging: row within 8-row group
  const int schunk = (lane & 7) ^ srow;    // pre-swizzled source chunk

  const int l15 = lane & 15;
  const int kg  = lane >> 4;

  f32x4 acc[4][4];
#pragma unroll
  for (int m = 0; m < 4; ++m)
#pragma unroll
    for (int n = 0; n < 4; ++n) acc[m][n] = (f32x4)0.f;

  for (int t = 0; t < DF / 64; ++t) {
    if (t) __syncthreads();                // prev iter's ds_reads are done
    const int kt = t * 64;
#pragma unroll
    for (int i = 0; i < 4; ++i) {
      const int q = wv * 4 + i;            // 1 KiB instruction q covers 8 rows
      const size_t goffA = (size_t)(brow + q * 8 + srow) * DF + kt + schunk * 8;
      const size_t goffB = (size_t)(bcol + q * 8 + srow) * DF + kt + schunk * 8;
      __builtin_amdgcn_global_load_lds(
          (const __attribute__((address_space(1))) void*)(Ebf + goffA),
          (__attribute__((address_space(3))) void*)(As + q * 512), 16, 0, 0);
      __builtin_amdgcn_global_load_lds(
          (const __attribute__((address_space(1))) void*)(Ebf + goffB),
          (__attribute__((address_space(3))) void*)(Bs + q * 512), 16, 0, 0);
    }
    __syncthreads();                       // drains vmcnt -> tile valid

#pragma unroll
    for (int s = 0; s < 2; ++s) {
      bf16x8 af[4], bfv[4];
#pragma unroll
      for (int m = 0; m < 4; ++m) {
        const int r    = wr * 64 + m * 16 + l15;
        const int slot = (s * 4 + kg) ^ (r & 7);
        af[m] = *reinterpret_cast<const bf16x8*>(&As[r * 64 + slot * 8]);
      }
#pragma unroll
      for (int n = 0; n < 4; ++n) {
        const int r    = wc * 64 + n * 16 + l15;
        const int slot = (s * 4 + kg) ^ (r & 7);
        bfv[n] = *reinterpret_cast<const bf16x8*>(&Bs[r * 64 + slot * 8]);
      }
#pragma unroll
      for (int m = 0; m < 4; ++m)
#pragma unroll
        for (int n = 0; n < 4; ++n)
          acc[m][n] = __builtin_amdgcn_mfma_f32_16x16x32_bf16(af[m], bfv[n], acc[m][n], 0, 0, 0);
    }
  }

  // ---- epilogue: d = sq_i + sq_j - 2g, mask same-class, per-row partial LSE
  float sqc[4]; int labc[4];
#pragma unroll
  for (int n = 0; n < 4; ++n) {
    const int gc = bcol + wc * 64 + n * 16 + l15;
    sqc[n] = sq[gc];
    labc[n] = (int)labels[gc];
  }
  const int pcol = blockIdx.x * 2 + wc;    // 128 partial columns per row
#pragma unroll
  for (int m = 0; m < 4; ++m) {
#pragma unroll
    for (int reg = 0; reg < 4; ++reg) {
      const int grow = brow + wr * 64 + m * 16 + kg * 4 + reg;
      const float sqr = sq[grow];
      const int labr = (int)labels[grow];
      float dv[4];
      float mx = -3.0e38f;
#pragma unroll
      for (int n = 0; n < 4; ++n) {
        const float g = acc[m][n][reg];
        const float d = sqr + sqc[n] - 2.0f * g;
        dv[n] = (labr != labc[n]) ? d : -3.0e38f;
        mx = fmaxf(mx, dv[n]);
      }
#pragma unroll
      for (int o = 1; o < 16; o <<= 1) mx = fmaxf(mx, __shfl_xor(mx, o));
      float se = 0.f;
#pragma unroll
      for (int n = 0; n < 4; ++n)
        se += (dv[n] > -2.9e38f) ? __expf(dv[n] - mx) : 0.f;
#pragma unroll
      for (int o = 1; o < 16; o <<= 1) se += __shfl_xor(se, o);
      if (l15 == 0) {
        Pm[(size_t)grow * 128 + pcol] = mx;
        Ps[(size_t)grow * 128 + pcol] = se;
      }
    }
  }
}

// ---------------- combine partials -> log_negsum per row ---------------------
__global__ void lse_reduce_kernel(const float* __restrict__ Pm,
                                  const float* __restrict__ Ps,
                                  float* __restrict__ ln) {
  const int row  = blockIdx.x * 4 + (threadIdx.x >> 6);
  const int lane = threadIdx.x & 63;
  const float m1 = Pm[(size_t)row * 128 + lane];
  const float m2 = Pm[(size_t)row * 128 + 64 + lane];
  const float s1 = Ps[(size_t)row * 128 + lane];
  const float s2 = Ps[(size_t)row * 128 + 64 + lane];
  float M = fmaxf(m1, m2);
#pragma unroll
  for (int o = 1; o < 64; o <<= 1) M = fmaxf(M, __shfl_xor(M, o));
  float S = s1 * __expf(m1 - M) + s2 * __expf(m2 - M);  // empty partials: s=0
#pragma unroll
  for (int o = 1; o < 64; o <<= 1) S += __shfl_xor(S, o);
  if (lane == 0) ln[row] = M + __logf(S);
}

// ---------------- per-class pair losses --------------------------------------
__global__ void pair_kernel(const unsigned short* __restrict__ Ebf,
                            const float* __restrict__ sq,
                            const float* __restrict__ ln,
                            const int* __restrict__ cnt,
                            const int* __restrict__ members,
                            float* __restrict__ csum2,
                            float* __restrict__ ccnt) {
  const int c = blockIdx.x >> 1, h = blockIdx.x & 1;  // 2 blocks per class
  const int tid = threadIdx.x, wv = tid >> 6, lane = tid & 63;
  const int slot = h * 4 + wv;                        // 0..7 wave slots
  const int k = cnt[c];
  __shared__ float wsums[4];

  float accum = 0.f;
  for (int a = 0; a < k - 1; ++a) {
    const int ia = members[c * MAXM + a];
    const bf16x8 va = *reinterpret_cast<const bf16x8*>(Ebf + (size_t)ia * DF + lane * 8);
    const float sqa = sq[ia];
    const float lna = ln[ia];                // member lists are index-sorted -> anchor = ia
    for (int b = a + 1 + slot; b < k; b += 8) {
      const int ib = members[c * MAXM + b];
      const bf16x8 vb = *reinterpret_cast<const bf16x8*>(Ebf + (size_t)ib * DF + lane * 8);
      float dot = 0.f;
#pragma unroll
      for (int j = 0; j < 8; ++j) dot += (float)va[j] * (float)vb[j];
#pragma unroll
      for (int o = 1; o < 64; o <<= 1) dot += __shfl_xor(dot, o);
      const float dist = sqa + sq[ib] - 2.0f * dot;
      const float z = lna - dist;
      const float pl = fmaxf(z, 0.f) + log1pf(__expf(-fabsf(z)));  // logaddexp(0,z)
      accum += pl;
    }
  }
  if (lane == 0) wsums[wv] = accum;
  __syncthreads();
  if (tid == 0) {
    csum2[c * 2 + h] = wsums[0] + wsums[1] + wsums[2] + wsums[3];
    if (h == 0) ccnt[c] = 0.5f * (float)k * (float)(k - 1);
  }
}

// ---------------- final scalar reduction --------------------------------------
__global__ void final_kernel(const float* __restrict__ csum2,
                             const float* __restrict__ ccnt,
                             float* __restrict__ out) {
  __shared__ float ssum[NCLS];
  __shared__ int   sval[NCLS];
  const int c = threadIdx.x;
  const float cs = csum2[2 * c] + csum2[2 * c + 1];
  const float cc = ccnt[c];
  const bool valid = cc > 0.f;
  ssum[c] = valid ? cs / cc : 0.f;
  sval[c] = valid ? 1 : 0;
  __syncthreads();
  if (c == 0) {
    float s = 0.f; int v = 0;
    for (int i = 0; i < NCLS; ++i) { s += ssum[i]; v += sval[i]; }
    out[0] = s / (float)v;
    out[1] = (float)v;
  }
}

extern "C" void kernel_launch(void* const* d_in, const int* in_sizes, int n_in,
                              void* d_out, int out_size, void* d_ws, size_t ws_size,
                              hipStream_t stream) {
  const float* E = (const float*)d_in[0];
  const long long* labels = (const long long*)d_in[1];
  float* out = (float*)d_out;

  char* w = (char*)d_ws;
  auto carve = [&](size_t bytes) { char* p = w; w += (bytes + 255) & ~(size_t)255; return p; };
  unsigned short* Ebf = (unsigned short*)carve((size_t)NPTS * DF * 2); // 8 MiB
  float* sq      = (float*)carve((size_t)NPTS * 4);
  float* Pm      = (float*)carve((size_t)NPTS * 128 * 4);              // 4 MiB
  float* Ps      = (float*)carve((size_t)NPTS * 128 * 4);              // 4 MiB
  float* ln      = (float*)carve((size_t)NPTS * 4);
  int*   cnt     = (int*)carve((size_t)NCLS * 4);
  int*   members = (int*)carve((size_t)NCLS * MAXM * 4);
  float* csum2   = (float*)carve((size_t)NCLS * 2 * 4);
  float* ccnt    = (float*)carve((size_t)NCLS * 4);

  prep_kernel<<<NPTS / 4, 256, 0, stream>>>(E, Ebf, sq);
  build_lists_kernel<<<NCLS, 64, 0, stream>>>(labels, cnt, members);
  gram_lse_kernel<<<dim3(64, 64), 256, 0, stream>>>(Ebf, sq, labels, Pm, Ps);
  lse_reduce_kernel<<<NPTS / 4, 256, 0, stream>>>(Pm, Ps, ln);
  pair_kernel<<<NCLS * 2, 256, 0, stream>>>(Ebf, sq, ln, cnt, members, csum2, ccnt);
  final_kernel<<<1, NCLS, 0, stream>>>(csum2, ccnt, out);
}

// Round 2
// 178.943 us; speedup vs baseline: 3.0944x; 3.0944x over previous
//
#include <hip/hip_runtime.h>
#include <cstdint>
#include <cstddef>

#define NPTS 8192
#define DF   512
#define NCLS 128
#define MAXM 192
#define PAIR_SPLIT 4

typedef __attribute__((ext_vector_type(8))) short   short8;
typedef __attribute__((ext_vector_type(8))) __bf16  bf16x8;
typedef __attribute__((ext_vector_type(4))) float   f32x4;
typedef __attribute__((ext_vector_type(4))) float   f4;

// ---------------- prep: fp32 -> bf16 copy + row squared norms ----------------
__global__ void prep_kernel(const float* __restrict__ E,
                            unsigned short* __restrict__ Ebf,
                            float* __restrict__ sq) {
  const int row  = blockIdx.x * 4 + (threadIdx.x >> 6);
  const int lane = threadIdx.x & 63;
  const float* rp = E + (size_t)row * DF + lane * 8;
  f4 x0 = *reinterpret_cast<const f4*>(rp);
  f4 x1 = *reinterpret_cast<const f4*>(rp + 4);
  float x[8] = {x0.x, x0.y, x0.z, x0.w, x1.x, x1.y, x1.z, x1.w};
  float s = 0.f;
  short8 o;
#pragma unroll
  for (int j = 0; j < 8; ++j) {
    s += x[j] * x[j];
    uint32_t u = __float_as_uint(x[j]);
    u += 0x7FFFu + ((u >> 16) & 1u);   // round-to-nearest-even bf16
    o[j] = (short)(u >> 16);
  }
  *reinterpret_cast<short8*>(Ebf + (size_t)row * DF + lane * 8) = o;
#pragma unroll
  for (int d = 1; d < 64; d <<= 1) s += __shfl_xor(s, d);
  if (lane == 0) sq[row] = s;
}

// ---------------- deterministic class member lists (wave ballot scan) --------
__global__ void build_lists_kernel(const long long* __restrict__ labels,
                                   int* __restrict__ cnt,
                                   int* __restrict__ members) {
  const int c    = blockIdx.x;     // one wave per class
  const int lane = threadIdx.x;    // blockDim = 64
  int base = 0;
  for (int chunk = 0; chunk < NPTS / 64; ++chunk) {
    const int idx = chunk * 64 + lane;
    const int lab = (int)labels[idx];
    const unsigned long long mask = __ballot(lab == c);
    if (lab == c) {
      const int prefix = __popcll(mask & ((1ull << lane) - 1ull));
      if (base + prefix < MAXM) members[c * MAXM + base + prefix] = idx;
    }
    base += __popcll(mask);
  }
  if (lane == 0) cnt[c] = (base < MAXM) ? base : MAXM;
}

// ---------------- main: bf16 MFMA Gram + fused masked partial LSE ------------
__global__ __launch_bounds__(256, 2)
void gram_lse_kernel(const unsigned short* __restrict__ Ebf,
                     const float* __restrict__ sq,
                     const long long* __restrict__ labels,
                     float* __restrict__ Pm, float* __restrict__ Ps) {
  __shared__ unsigned short As[128 * 64];   // 16 KiB, XOR-swizzled 16B chunks
  __shared__ unsigned short Bs[128 * 64];   // 16 KiB

  const int tid  = threadIdx.x;
  const int lane = tid & 63;
  const int wv   = tid >> 6;
  const int wr   = wv >> 1, wc = wv & 1;
  const int brow = blockIdx.y * 128;
  const int bcol = blockIdx.x * 128;

  const int srow   = lane >> 3;            // staging: row within 8-row group
  const int schunk = (lane & 7) ^ srow;    // pre-swizzled source chunk

  const int l15 = lane & 15;
  const int kg  = lane >> 4;

  f32x4 acc[4][4];
#pragma unroll
  for (int m = 0; m < 4; ++m)
#pragma unroll
    for (int n = 0; n < 4; ++n) acc[m][n] = (f32x4)0.f;

  for (int t = 0; t < DF / 64; ++t) {
    if (t) __syncthreads();                // prev iter's ds_reads are done
    const int kt = t * 64;
#pragma unroll
    for (int i = 0; i < 4; ++i) {
      const int q = wv * 4 + i;            // 1 KiB instruction q covers 8 rows
      const size_t goffA = (size_t)(brow + q * 8 + srow) * DF + kt + schunk * 8;
      const size_t goffB = (size_t)(bcol + q * 8 + srow) * DF + kt + schunk * 8;
      __builtin_amdgcn_global_load_lds(
          (const __attribute__((address_space(1))) void*)(Ebf + goffA),
          (__attribute__((address_space(3))) void*)(As + q * 512), 16, 0, 0);
      __builtin_amdgcn_global_load_lds(
          (const __attribute__((address_space(1))) void*)(Ebf + goffB),
          (__attribute__((address_space(3))) void*)(Bs + q * 512), 16, 0, 0);
    }
    __syncthreads();                       // drains vmcnt -> tile valid

#pragma unroll
    for (int s = 0; s < 2; ++s) {
      bf16x8 af[4], bfv[4];
#pragma unroll
      for (int m = 0; m < 4; ++m) {
        const int r    = wr * 64 + m * 16 + l15;
        const int slot = (s * 4 + kg) ^ (r & 7);
        af[m] = *reinterpret_cast<const bf16x8*>(&As[r * 64 + slot * 8]);
      }
#pragma unroll
      for (int n = 0; n < 4; ++n) {
        const int r    = wc * 64 + n * 16 + l15;
        const int slot = (s * 4 + kg) ^ (r & 7);
        bfv[n] = *reinterpret_cast<const bf16x8*>(&Bs[r * 64 + slot * 8]);
      }
#pragma unroll
      for (int m = 0; m < 4; ++m)
#pragma unroll
        for (int n = 0; n < 4; ++n)
          acc[m][n] = __builtin_amdgcn_mfma_f32_16x16x32_bf16(af[m], bfv[n], acc[m][n], 0, 0, 0);
    }
  }

  // ---- epilogue: d = sq_i + sq_j - 2g, mask same-class, per-row partial LSE
  float sqc[4]; int labc[4];
#pragma unroll
  for (int n = 0; n < 4; ++n) {
    const int gc = bcol + wc * 64 + n * 16 + l15;
    sqc[n] = sq[gc];
    labc[n] = (int)labels[gc];
  }
  const int pcol = blockIdx.x * 2 + wc;    // 128 partial columns per row
#pragma unroll
  for (int m = 0; m < 4; ++m) {
#pragma unroll
    for (int reg = 0; reg < 4; ++reg) {
      const int grow = brow + wr * 64 + m * 16 + kg * 4 + reg;
      const float sqr = sq[grow];
      const int labr = (int)labels[grow];
      float dv[4];
      float mx = -3.0e38f;
#pragma unroll
      for (int n = 0; n < 4; ++n) {
        const float g = acc[m][n][reg];
        const float d = sqr + sqc[n] - 2.0f * g;
        dv[n] = (labr != labc[n]) ? d : -3.0e38f;
        mx = fmaxf(mx, dv[n]);
      }
#pragma unroll
      for (int o = 1; o < 16; o <<= 1) mx = fmaxf(mx, __shfl_xor(mx, o));
      float se = 0.f;
#pragma unroll
      for (int n = 0; n < 4; ++n)
        se += (dv[n] > -2.9e38f) ? __expf(dv[n] - mx) : 0.f;
#pragma unroll
      for (int o = 1; o < 16; o <<= 1) se += __shfl_xor(se, o);
      if (l15 == 0) {
        Pm[(size_t)grow * 128 + pcol] = mx;
        Ps[(size_t)grow * 128 + pcol] = se;
      }
    }
  }
}

// ---------------- combine partials -> log_negsum per row ---------------------
__global__ void lse_reduce_kernel(const float* __restrict__ Pm,
                                  const float* __restrict__ Ps,
                                  float* __restrict__ ln) {
  const int row  = blockIdx.x * 4 + (threadIdx.x >> 6);
  const int lane = threadIdx.x & 63;
  const float m1 = Pm[(size_t)row * 128 + lane];
  const float m2 = Pm[(size_t)row * 128 + 64 + lane];
  const float s1 = Ps[(size_t)row * 128 + lane];
  const float s2 = Ps[(size_t)row * 128 + 64 + lane];
  float M = fmaxf(m1, m2);
#pragma unroll
  for (int o = 1; o < 64; o <<= 1) M = fmaxf(M, __shfl_xor(M, o));
  float S = s1 * __expf(m1 - M) + s2 * __expf(m2 - M);  // empty partials: s=0
#pragma unroll
  for (int o = 1; o < 64; o <<= 1) S += __shfl_xor(S, o);
  if (lane == 0) ln[row] = M + __logf(S);
}

// ---------------- per-class pair losses via MFMA class-Gram ------------------
// grid = NCLS * PAIR_SPLIT blocks, 256 threads. Each (class, h) block's 4
// waves stride over the upper-triangular 16x16 tiles of the class Gram.
__global__ __launch_bounds__(256)
void pair_mfma_kernel(const unsigned short* __restrict__ Ebf,
                      const float* __restrict__ sq,
                      const float* __restrict__ ln,
                      const int* __restrict__ cnt,
                      const int* __restrict__ members,
                      float* __restrict__ csum,
                      float* __restrict__ ccnt) {
  const int c   = blockIdx.x / PAIR_SPLIT;
  const int h   = blockIdx.x % PAIR_SPLIT;
  const int tid = threadIdx.x, wv = tid >> 6, lane = tid & 63;
  const int l15 = lane & 15, kg = lane >> 4;
  const int k = cnt[c];
  __shared__ float wsums[4];

  if (k < 2) {
    if (tid == 0) { csum[c * PAIR_SPLIT + h] = 0.f; if (h == 0) ccnt[c] = 0.f; }
    return;
  }

  const int nt    = (k + 15) >> 4;            // 16-row tiles per dim
  const int total = nt * (nt + 1) / 2;        // upper-triangular tiles
  const int slot  = h * 4 + wv;               // 0..15, strides tiles

  const int* mem = members + c * MAXM;
  float accum = 0.f;

  for (int t = slot; t < total; t += 4 * PAIR_SPLIT) {
    // decode linear upper-tri index -> (ti, tj), ti <= tj   (wave-uniform)
    int ti = 0, rem = t;
    while (rem >= nt - ti) { rem -= nt - ti; ++ti; }
    const int tj = ti + rem;

    // fragment source rows (clamped gather; invalid lanes masked in epilogue)
    const int apos_f = ti * 16 + l15;
    const int bpos_f = tj * 16 + l15;
    const int arow = mem[apos_f < k ? apos_f : k - 1];
    const int brow = mem[bpos_f < k ? bpos_f : k - 1];
    const unsigned short* ap = Ebf + (size_t)arow * DF + kg * 8;
    const unsigned short* bp = Ebf + (size_t)brow * DF + kg * 8;

    f32x4 acc = (f32x4)0.f;
#pragma unroll
    for (int s = 0; s < DF / 32; ++s) {
      bf16x8 a = *reinterpret_cast<const bf16x8*>(ap + s * 32);
      bf16x8 b = *reinterpret_cast<const bf16x8*>(bp + s * 32);
      acc = __builtin_amdgcn_mfma_f32_16x16x32_bf16(a, b, acc, 0, 0, 0);
    }

    // epilogue: C layout col = l15, row = kg*4 + reg
    const int b_pos = tj * 16 + l15;
    if (b_pos < k) {
      const int ib = mem[b_pos];
      const float sqb = sq[ib];
#pragma unroll
      for (int reg = 0; reg < 4; ++reg) {
        const int a_pos = ti * 16 + kg * 4 + reg;
        if (a_pos < b_pos) {
          const int ia = mem[a_pos];
          const float dist = sq[ia] + sqb - 2.0f * acc[reg];
          const float z = ln[ia] - dist;
          accum += fmaxf(z, 0.f) + log1pf(__expf(-fabsf(z)));
        }
      }
    }
  }

#pragma unroll
  for (int o = 1; o < 64; o <<= 1) accum += __shfl_xor(accum, o);
  if (lane == 0) wsums[wv] = accum;
  __syncthreads();
  if (tid == 0) {
    csum[c * PAIR_SPLIT + h] = wsums[0] + wsums[1] + wsums[2] + wsums[3];
    if (h == 0) ccnt[c] = 0.5f * (float)k * (float)(k - 1);
  }
}

// ---------------- final scalar reduction --------------------------------------
__global__ void final_kernel(const float* __restrict__ csum,
                             const float* __restrict__ ccnt,
                             float* __restrict__ out) {
  __shared__ float ssum[NCLS];
  __shared__ int   sval[NCLS];
  const int c = threadIdx.x;
  float cs = 0.f;
#pragma unroll
  for (int i = 0; i < PAIR_SPLIT; ++i) cs += csum[c * PAIR_SPLIT + i];
  const float cc = ccnt[c];
  const bool valid = cc > 0.f;
  ssum[c] = valid ? cs / cc : 0.f;
  sval[c] = valid ? 1 : 0;
  __syncthreads();
  if (c == 0) {
    float s = 0.f; int v = 0;
    for (int i = 0; i < NCLS; ++i) { s += ssum[i]; v += sval[i]; }
    out[0] = s / (float)v;
    out[1] = (float)v;
  }
}

extern "C" void kernel_launch(void* const* d_in, const int* in_sizes, int n_in,
                              void* d_out, int out_size, void* d_ws, size_t ws_size,
                              hipStream_t stream) {
  const float* E = (const float*)d_in[0];
  const long long* labels = (const long long*)d_in[1];
  float* out = (float*)d_out;

  char* w = (char*)d_ws;
  auto carve = [&](size_t bytes) { char* p = w; w += (bytes + 255) & ~(size_t)255; return p; };
  unsigned short* Ebf = (unsigned short*)carve((size_t)NPTS * DF * 2); // 8 MiB
  float* sq      = (float*)carve((size_t)NPTS * 4);
  float* Pm      = (float*)carve((size_t)NPTS * 128 * 4);              // 4 MiB
  float* Ps      = (float*)carve((size_t)NPTS * 128 * 4);              // 4 MiB
  float* ln      = (float*)carve((size_t)NPTS * 4);
  int*   cnt     = (int*)carve((size_t)NCLS * 4);
  int*   members = (int*)carve((size_t)NCLS * MAXM * 4);
  float* csum    = (float*)carve((size_t)NCLS * PAIR_SPLIT * 4);
  float* ccnt    = (float*)carve((size_t)NCLS * 4);

  prep_kernel<<<NPTS / 4, 256, 0, stream>>>(E, Ebf, sq);
  build_lists_kernel<<<NCLS, 64, 0, stream>>>(labels, cnt, members);
  gram_lse_kernel<<<dim3(64, 64), 256, 0, stream>>>(Ebf, sq, labels, Pm, Ps);
  lse_reduce_kernel<<<NPTS / 4, 256, 0, stream>>>(Pm, Ps, ln);
  pair_mfma_kernel<<<NCLS * PAIR_SPLIT, 256, 0, stream>>>(Ebf, sq, ln, cnt, members, csum, ccnt);
  final_kernel<<<1, NCLS, 0, stream>>>(csum, ccnt, out);
}

// Round 3
// 152.189 us; speedup vs baseline: 3.6384x; 1.1758x over previous
//
#include <hip/hip_runtime.h>
#include <cstdint>
#include <cstddef>

#define NPTS 8192
#define DF   512
#define NCLS 128
#define MAXM 192
#define PAIR_SPLIT 4

typedef __attribute__((ext_vector_type(8))) short   short8;
typedef __attribute__((ext_vector_type(8))) __bf16  bf16x8;
typedef __attribute__((ext_vector_type(4))) float   f32x4;
typedef __attribute__((ext_vector_type(4))) float   f4;

// ---------------- prep: fp32 -> bf16 copy + row squared norms ----------------
__global__ void prep_kernel(const float* __restrict__ E,
                            unsigned short* __restrict__ Ebf,
                            float* __restrict__ sq) {
  const int row  = blockIdx.x * 4 + (threadIdx.x >> 6);
  const int lane = threadIdx.x & 63;
  const float* rp = E + (size_t)row * DF + lane * 8;
  f4 x0 = *reinterpret_cast<const f4*>(rp);
  f4 x1 = *reinterpret_cast<const f4*>(rp + 4);
  float x[8] = {x0.x, x0.y, x0.z, x0.w, x1.x, x1.y, x1.z, x1.w};
  float s = 0.f;
  short8 o;
#pragma unroll
  for (int j = 0; j < 8; ++j) {
    s += x[j] * x[j];
    uint32_t u = __float_as_uint(x[j]);
    u += 0x7FFFu + ((u >> 16) & 1u);   // round-to-nearest-even bf16
    o[j] = (short)(u >> 16);
  }
  *reinterpret_cast<short8*>(Ebf + (size_t)row * DF + lane * 8) = o;
#pragma unroll
  for (int d = 1; d < 64; d <<= 1) s += __shfl_xor(s, d);
  if (lane == 0) sq[row] = s;
}

// ---------------- deterministic class member lists (wave ballot scan) --------
__global__ void build_lists_kernel(const long long* __restrict__ labels,
                                   int* __restrict__ cnt,
                                   int* __restrict__ members) {
  const int c    = blockIdx.x;     // one wave per class
  const int lane = threadIdx.x;    // blockDim = 64
  int base = 0;
  for (int chunk = 0; chunk < NPTS / 64; ++chunk) {
    const int idx = chunk * 64 + lane;
    const int lab = (int)labels[idx];
    const unsigned long long mask = __ballot(lab == c);
    if (lab == c) {
      const int prefix = __popcll(mask & ((1ull << lane) - 1ull));
      if (base + prefix < MAXM) members[c * MAXM + base + prefix] = idx;
    }
    base += __popcll(mask);
  }
  if (lane == 0) cnt[c] = (base < MAXM) ? base : MAXM;
}

// ---------------- main: bf16 MFMA Gram + fused masked partial LSE ------------
// Symmetric: only upper-triangular blocks (bi <= bj) run. Off-diagonal blocks
// emit BOTH row-side partials (reduce over cols) and transpose-side partials
// (reduce the same masked distances over rows -> partials for the col rows).
__global__ __launch_bounds__(256, 2)
void gram_lse_kernel(const unsigned short* __restrict__ Ebf,
                     const float* __restrict__ sq,
                     const long long* __restrict__ labels,
                     float* __restrict__ Pm, float* __restrict__ Ps) {
  const int bix = blockIdx.x;   // column block
  const int biy = blockIdx.y;   // row block
  if (biy > bix) return;        // lower triangle handled by transpose side

  __shared__ unsigned short As[128 * 64];   // 16 KiB, XOR-swizzled 16B chunks
  __shared__ unsigned short Bs[128 * 64];   // 16 KiB

  const int tid  = threadIdx.x;
  const int lane = tid & 63;
  const int wv   = tid >> 6;
  const int wr   = wv >> 1, wc = wv & 1;
  const int brow = biy * 128;
  const int bcol = bix * 128;

  const int srow   = lane >> 3;            // staging: row within 8-row group
  const int schunk = (lane & 7) ^ srow;    // pre-swizzled source chunk

  const int l15 = lane & 15;
  const int kg  = lane >> 4;

  f32x4 acc[4][4];
#pragma unroll
  for (int m = 0; m < 4; ++m)
#pragma unroll
    for (int n = 0; n < 4; ++n) acc[m][n] = (f32x4)0.f;

  for (int t = 0; t < DF / 64; ++t) {
    if (t) __syncthreads();                // prev iter's ds_reads are done
    const int kt = t * 64;
#pragma unroll
    for (int i = 0; i < 4; ++i) {
      const int q = wv * 4 + i;            // 1 KiB instruction q covers 8 rows
      const size_t goffA = (size_t)(brow + q * 8 + srow) * DF + kt + schunk * 8;
      const size_t goffB = (size_t)(bcol + q * 8 + srow) * DF + kt + schunk * 8;
      __builtin_amdgcn_global_load_lds(
          (const __attribute__((address_space(1))) void*)(Ebf + goffA),
          (__attribute__((address_space(3))) void*)(As + q * 512), 16, 0, 0);
      __builtin_amdgcn_global_load_lds(
          (const __attribute__((address_space(1))) void*)(Ebf + goffB),
          (__attribute__((address_space(3))) void*)(Bs + q * 512), 16, 0, 0);
    }
    __syncthreads();                       // drains vmcnt -> tile valid

#pragma unroll
    for (int s = 0; s < 2; ++s) {
      bf16x8 af[4], bfv[4];
#pragma unroll
      for (int m = 0; m < 4; ++m) {
        const int r    = wr * 64 + m * 16 + l15;
        const int slot = (s * 4 + kg) ^ (r & 7);
        af[m] = *reinterpret_cast<const bf16x8*>(&As[r * 64 + slot * 8]);
      }
#pragma unroll
      for (int n = 0; n < 4; ++n) {
        const int r    = wc * 64 + n * 16 + l15;
        const int slot = (s * 4 + kg) ^ (r & 7);
        bfv[n] = *reinterpret_cast<const bf16x8*>(&Bs[r * 64 + slot * 8]);
      }
#pragma unroll
      for (int m = 0; m < 4; ++m)
#pragma unroll
        for (int n = 0; n < 4; ++n)
          acc[m][n] = __builtin_amdgcn_mfma_f32_16x16x32_bf16(af[m], bfv[n], acc[m][n], 0, 0, 0);
    }
  }

  // ---- epilogue pass 1: d = sq_i + sq_j - 2g, mask same-class (stored back
  //      into acc), per-row partial LSE over this wave's 64-col slice.
  float sqc[4]; int labc[4];
#pragma unroll
  for (int n = 0; n < 4; ++n) {
    const int gc = bcol + wc * 64 + n * 16 + l15;
    sqc[n] = sq[gc];
    labc[n] = (int)labels[gc];
  }
  const int pcol = bix * 2 + wc;           // row-side partial slot
#pragma unroll
  for (int m = 0; m < 4; ++m) {
#pragma unroll
    for (int reg = 0; reg < 4; ++reg) {
      const int grow = brow + wr * 64 + m * 16 + kg * 4 + reg;
      const float sqr = sq[grow];
      const int labr = (int)labels[grow];
      float dv[4];
      float mx = -3.0e38f;
#pragma unroll
      for (int n = 0; n < 4; ++n) {
        const float g = acc[m][n][reg];
        const float d = sqr + sqc[n] - 2.0f * g;
        const float v = (labr != labc[n]) ? d : -3.0e38f;
        dv[n] = v;
        acc[m][n][reg] = v;                // keep masked distance for pass 2
        mx = fmaxf(mx, v);
      }
#pragma unroll
      for (int o = 1; o < 16; o <<= 1) mx = fmaxf(mx, __shfl_xor(mx, o));
      float se = 0.f;
#pragma unroll
      for (int n = 0; n < 4; ++n)
        se += (dv[n] > -2.9e38f) ? __expf(dv[n] - mx) : 0.f;
#pragma unroll
      for (int o = 1; o < 16; o <<= 1) se += __shfl_xor(se, o);
      if (l15 == 0) {
        Pm[(size_t)grow * 128 + pcol] = mx;
        Ps[(size_t)grow * 128 + pcol] = se;
      }
    }
  }

  // ---- epilogue pass 2 (off-diagonal only): transpose-side partials.
  //      For each column (= output row gcol), reduce masked distances over
  //      this wave's 64 rows: in-lane over (m, reg), cross-lane over kg.
  if (biy != bix) {
    const int tpcol = biy * 2 + wr;        // partial slot indexed by row-block half
#pragma unroll
    for (int n = 0; n < 4; ++n) {
      float tm = -3.0e38f;
#pragma unroll
      for (int m = 0; m < 4; ++m)
#pragma unroll
        for (int reg = 0; reg < 4; ++reg)
          tm = fmaxf(tm, acc[m][n][reg]);
      tm = fmaxf(tm, __shfl_xor(tm, 16));
      tm = fmaxf(tm, __shfl_xor(tm, 32));
      float ts = 0.f;
#pragma unroll
      for (int m = 0; m < 4; ++m)
#pragma unroll
        for (int reg = 0; reg < 4; ++reg) {
          const float v = acc[m][n][reg];
          ts += (v > -2.9e38f) ? __expf(v - tm) : 0.f;
        }
      ts += __shfl_xor(ts, 16);
      ts += __shfl_xor(ts, 32);
      if (kg == 0) {
        const int gcol = bcol + wc * 64 + n * 16 + l15;
        Pm[(size_t)gcol * 128 + tpcol] = tm;
        Ps[(size_t)gcol * 128 + tpcol] = ts;
      }
    }
  }
}

// ---------------- combine partials -> log_negsum per row ---------------------
__global__ void lse_reduce_kernel(const float* __restrict__ Pm,
                                  const float* __restrict__ Ps,
                                  float* __restrict__ ln) {
  const int row  = blockIdx.x * 4 + (threadIdx.x >> 6);
  const int lane = threadIdx.x & 63;
  const float m1 = Pm[(size_t)row * 128 + lane];
  const float m2 = Pm[(size_t)row * 128 + 64 + lane];
  const float s1 = Ps[(size_t)row * 128 + lane];
  const float s2 = Ps[(size_t)row * 128 + 64 + lane];
  float M = fmaxf(m1, m2);
#pragma unroll
  for (int o = 1; o < 64; o <<= 1) M = fmaxf(M, __shfl_xor(M, o));
  float S = s1 * __expf(m1 - M) + s2 * __expf(m2 - M);  // empty partials: s=0
#pragma unroll
  for (int o = 1; o < 64; o <<= 1) S += __shfl_xor(S, o);
  if (lane == 0) ln[row] = M + __logf(S);
}

// ---------------- per-class pair losses via MFMA class-Gram ------------------
__global__ __launch_bounds__(256)
void pair_mfma_kernel(const unsigned short* __restrict__ Ebf,
                      const float* __restrict__ sq,
                      const float* __restrict__ ln,
                      const int* __restrict__ cnt,
                      const int* __restrict__ members,
                      float* __restrict__ csum,
                      float* __restrict__ ccnt) {
  const int c   = blockIdx.x / PAIR_SPLIT;
  const int h   = blockIdx.x % PAIR_SPLIT;
  const int tid = threadIdx.x, wv = tid >> 6, lane = tid & 63;
  const int l15 = lane & 15, kg = lane >> 4;
  const int k = cnt[c];
  __shared__ float wsums[4];

  if (k < 2) {
    if (tid == 0) { csum[c * PAIR_SPLIT + h] = 0.f; if (h == 0) ccnt[c] = 0.f; }
    return;
  }

  const int nt    = (k + 15) >> 4;            // 16-row tiles per dim
  const int total = nt * (nt + 1) / 2;        // upper-triangular tiles
  const int slot  = h * 4 + wv;               // 0..15, strides tiles

  const int* mem = members + c * MAXM;
  float accum = 0.f;

  for (int t = slot; t < total; t += 4 * PAIR_SPLIT) {
    int ti = 0, rem = t;
    while (rem >= nt - ti) { rem -= nt - ti; ++ti; }
    const int tj = ti + rem;

    const int apos_f = ti * 16 + l15;
    const int bpos_f = tj * 16 + l15;
    const int arow = mem[apos_f < k ? apos_f : k - 1];
    const int brow = mem[bpos_f < k ? bpos_f : k - 1];
    const unsigned short* ap = Ebf + (size_t)arow * DF + kg * 8;
    const unsigned short* bp = Ebf + (size_t)brow * DF + kg * 8;

    f32x4 acc = (f32x4)0.f;
#pragma unroll
    for (int s = 0; s < DF / 32; ++s) {
      bf16x8 a = *reinterpret_cast<const bf16x8*>(ap + s * 32);
      bf16x8 b = *reinterpret_cast<const bf16x8*>(bp + s * 32);
      acc = __builtin_amdgcn_mfma_f32_16x16x32_bf16(a, b, acc, 0, 0, 0);
    }

    const int b_pos = tj * 16 + l15;
    if (b_pos < k) {
      const int ib = mem[b_pos];
      const float sqb = sq[ib];
#pragma unroll
      for (int reg = 0; reg < 4; ++reg) {
        const int a_pos = ti * 16 + kg * 4 + reg;
        if (a_pos < b_pos) {
          const int ia = mem[a_pos];
          const float dist = sq[ia] + sqb - 2.0f * acc[reg];
          const float z = ln[ia] - dist;
          accum += fmaxf(z, 0.f) + log1pf(__expf(-fabsf(z)));
        }
      }
    }
  }

#pragma unroll
  for (int o = 1; o < 64; o <<= 1) accum += __shfl_xor(accum, o);
  if (lane == 0) wsums[wv] = accum;
  __syncthreads();
  if (tid == 0) {
    csum[c * PAIR_SPLIT + h] = wsums[0] + wsums[1] + wsums[2] + wsums[3];
    if (h == 0) ccnt[c] = 0.5f * (float)k * (float)(k - 1);
  }
}

// ---------------- final scalar reduction --------------------------------------
__global__ void final_kernel(const float* __restrict__ csum,
                             const float* __restrict__ ccnt,
                             float* __restrict__ out) {
  __shared__ float ssum[NCLS];
  __shared__ int   sval[NCLS];
  const int c = threadIdx.x;
  float cs = 0.f;
#pragma unroll
  for (int i = 0; i < PAIR_SPLIT; ++i) cs += csum[c * PAIR_SPLIT + i];
  const float cc = ccnt[c];
  const bool valid = cc > 0.f;
  ssum[c] = valid ? cs / cc : 0.f;
  sval[c] = valid ? 1 : 0;
  __syncthreads();
  if (c == 0) {
    float s = 0.f; int v = 0;
    for (int i = 0; i < NCLS; ++i) { s += ssum[i]; v += sval[i]; }
    out[0] = s / (float)v;
    out[1] = (float)v;
  }
}

extern "C" void kernel_launch(void* const* d_in, const int* in_sizes, int n_in,
                              void* d_out, int out_size, void* d_ws, size_t ws_size,
                              hipStream_t stream) {
  const float* E = (const float*)d_in[0];
  const long long* labels = (const long long*)d_in[1];
  float* out = (float*)d_out;

  char* w = (char*)d_ws;
  auto carve = [&](size_t bytes) { char* p = w; w += (bytes + 255) & ~(size_t)255; return p; };
  unsigned short* Ebf = (unsigned short*)carve((size_t)NPTS * DF * 2); // 8 MiB
  float* sq      = (float*)carve((size_t)NPTS * 4);
  float* Pm      = (float*)carve((size_t)NPTS * 128 * 4);              // 4 MiB
  float* Ps      = (float*)carve((size_t)NPTS * 128 * 4);              // 4 MiB
  float* ln      = (float*)carve((size_t)NPTS * 4);
  int*   cnt     = (int*)carve((size_t)NCLS * 4);
  int*   members = (int*)carve((size_t)NCLS * MAXM * 4);
  float* csum    = (float*)carve((size_t)NCLS * PAIR_SPLIT * 4);
  float* ccnt    = (float*)carve((size_t)NCLS * 4);

  prep_kernel<<<NPTS / 4, 256, 0, stream>>>(E, Ebf, sq);
  build_lists_kernel<<<NCLS, 64, 0, stream>>>(labels, cnt, members);
  gram_lse_kernel<<<dim3(64, 64), 256, 0, stream>>>(Ebf, sq, labels, Pm, Ps);
  lse_reduce_kernel<<<NPTS / 4, 256, 0, stream>>>(Pm, Ps, ln);
  pair_mfma_kernel<<<NCLS * PAIR_SPLIT, 256, 0, stream>>>(Ebf, sq, ln, cnt, members, csum, ccnt);
  final_kernel<<<1, NCLS, 0, stream>>>(csum, ccnt, out);
}